// Round 6
// baseline (408.778 us; speedup 1.0000x reference)
//
#include <hip/hip_runtime.h>

#define TSTEPS 1024
#define CH 2               // chains per block; replicated 8x across MFMA m-rows

typedef _Float16 half8  __attribute__((ext_vector_type(8)));
typedef float    f32x4  __attribute__((ext_vector_type(4)));

#define MFMA16(A_, B_, C_) __builtin_amdgcn_mfma_f32_16x16x32_f16((A_), (B_), (C_), 0, 0, 0)

__device__ __forceinline__ float fast_rcp(float x) { return __builtin_amdgcn_rcpf(x); }
__device__ __forceinline__ float fast_exp2(float x) {
#if __has_builtin(__builtin_amdgcn_exp2f)
    return __builtin_amdgcn_exp2f(x);
#else
    return exp2f(x);
#endif
}

// load 8 consecutive fp32, scale, convert to packed f16 MFMA fragment
__device__ __forceinline__ half8 load_w8s(const float* p, float s) {
    const float4 a = ((const float4*)p)[0];
    const float4 b = ((const float4*)p)[1];
    half8 r;
    r[0] = (_Float16)(s * a.x); r[1] = (_Float16)(s * a.y);
    r[2] = (_Float16)(s * a.z); r[3] = (_Float16)(s * a.w);
    r[4] = (_Float16)(s * b.x); r[5] = (_Float16)(s * b.y);
    r[6] = (_Float16)(s * b.z); r[7] = (_Float16)(s * b.w);
    return r;
}

// R19 = R17 structure (WIN baseline 272us: operand-swapped MFMA,
// row-replicated A, in-register preacts, 1 gate-triple/lane, chained MFMA
// accumulation) at CH=2 -> 512 blocks -> 2 BLOCKS PER CU.
// R18 post-mortem: SIMD rebalance + parallel partials REGRESSED (+16us,
// VALUBusy +2.7 from extra v_adds) -> tick is NOT worst-SIMD-issue-bound;
// it's the serial latency chain (barrier -> ds_read ~120cy -> MFMA lat ->
// triple ~100cy -> ds_write -> barrier drain ~ 500-600cy). R18 reverted.
// This round attacks the chain with TLP (m114: MFMA/VALU pipes co-issue
// across waves; barrier-stalled waves are free): two independent blocks
// per CU, each with its own barrier, mutually hide their chains.
// Issue audit per CU per 2 ticks: MFMA ~408cy, VALU ~380cy (separate
// pipes), DS ~500cy -- all under the ~640cy chain, so hiding is feasible.
// CH=2 mapping: A[m=nl] = h1[chain nl>>3][k] (8x replication). C/D rows
// 0..7 = chain 0, 8..15 = chain 1 -> lane's gate chain cch = quad>>1;
// each (chain,unit) is computed by 2 lanes (quad 2c, 2c+1): identical
// values, duplicate LDS writes benign, global store guarded to quad even.
//   waves 0..3: GRU1 unit-tile wid (units wid*16+nl): 6 MFMA + 1 triple.
//   waves 4..5: GRU2 (units (wid-4)*16+nl), ONE STEP BEHIND: 9 MFMA + 1.
// LDS strides 80/48 (uniform 2-way). One barrier/tick. R8 parity: at tick
// t, h1(t-1) in s_h1[(t+1)&1]; GRU2 reads h2(t-2) from s_h2[t&1], writes
// h2(t-1) to s_h2[(t+1)&1]. exp2 pre-scaled gates (R10).
__global__ __launch_bounds__(384, 1)
void gru2_encoder(const float* __restrict__ x,
                  const float* __restrict__ W_ih1,
                  const float* __restrict__ W_hh1,
                  const float* __restrict__ b_ih1,
                  const float* __restrict__ b_hh1,
                  const float* __restrict__ W_ih2,
                  const float* __restrict__ W_hh2,
                  const float* __restrict__ b_ih2,
                  const float* __restrict__ b_hh2,
                  float* __restrict__ out)
{
    const int blk  = blockIdx.x;    // 512 blocks, CH=2 chains each
    const int tid  = threadIdx.x;   // 384
    const int lane = tid & 63;
    const int wid  = tid >> 6;      // 0..5
    const int nl   = lane & 15;     // MFMA non-k lane index (unit col)
    const int quad = lane >> 4;     // 0..3
    const int cch  = quad >> 1;     // this lane's gate CHAIN (0..1)
    const int ac   = nl >> 3;       // chain this lane's A-row replicates (0..1)
    const int chain0 = blk * CH;

    const float SNEG = -1.44269504f;       // -log2(e)
    const float SP2  =  2.88539008f;       // 2*log2(e)

    // strides padded for uniform low-way bank access
    __shared__ __align__(16) _Float16 s_h1[2][2][80];   // [par][chain][unit64 pad80]
    __shared__ __align__(16) _Float16 s_h2[2][2][48];   // [par][chain][unit32 pad48]
    __shared__ __align__(16) _Float16 s_x[TSTEPS][2];   // x f16, [t][chain]

    // ---- one-time staging
    for (int idx = tid; idx < 2 * TSTEPS; idx += 384) {
        const int m = idx >> 10, t = idx & (TSTEPS - 1);
        s_x[t][m] = (_Float16)x[(size_t)(chain0 + m) * TSTEPS + t];
    }
    {
        _Float16* p1 = &s_h1[0][0][0];
        for (int idx = tid; idx < 2 * 2 * 80; idx += 384) p1[idx] = (_Float16)0.0f;
        _Float16* p2 = &s_h2[0][0][0];
        for (int idx = tid; idx < 2 * 2 * 48; idx += 384) p2[idx] = (_Float16)0.0f;
    }
    __syncthreads();

    if (wid < 4) {
        // ================= GRU1, unit-tile wid: units wid*16+nl =================
        const int un = wid * 16 + nl;        // this lane's output unit (n-col)
        // weights as B operand: B[k=quad*8+jj][n=nl] = W_hh1[un][k] (pre-scaled)
        const half8 Br0 = load_w8s(W_hh1 + (size_t)(un)        * 64 + quad * 8,      SNEG);
        const half8 Br1 = load_w8s(W_hh1 + (size_t)(un)        * 64 + 32 + quad * 8, SNEG);
        const half8 Bz0 = load_w8s(W_hh1 + (size_t)(64 + un)   * 64 + quad * 8,      SNEG);
        const half8 Bz1 = load_w8s(W_hh1 + (size_t)(64 + un)   * 64 + 32 + quad * 8, SNEG);
        const half8 Bn0 = load_w8s(W_hh1 + (size_t)(128 + un)  * 64 + quad * 8,      SP2);
        const half8 Bn1 = load_w8s(W_hh1 + (size_t)(128 + un)  * 64 + 32 + quad * 8, SP2);
        // bias depends on unit (col) only -> splat across the 4 C rows
        const float cr = SNEG * (b_ih1[un] + b_hh1[un]);
        const float cz = SNEG * (b_ih1[64 + un] + b_hh1[64 + un]);
        const float cn = SP2 * b_hh1[128 + un];
        const f32x4 Cr = {cr, cr, cr, cr};
        const f32x4 Cz = {cz, cz, cz, cz};
        const f32x4 Cn = {cn, cn, cn, cn};
        // x-path scalars for this lane's unit
        const float twr = SNEG * W_ih1[un];
        const float twz = SNEG * W_ih1[64 + un];
        const float twn = SP2  * W_ih1[128 + un];
        const float tbn = SP2  * b_ih1[128 + un];

        float h1s = 0.0f;   // h1[chain=cch][unit=un]

        for (int t = 0; t <= TSTEPS; ++t) {
            if (t < TSTEPS) {
                const int pr = (t + 1) & 1;
                // A = h1(t-1), chain replicated over 8 rows: A[m=nl] = h1[nl>>3][k]
                const half8 A0 = *(const half8*)&s_h1[pr][ac][quad * 8];
                const half8 A1 = *(const half8*)&s_h1[pr][ac][32 + quad * 8];
                f32x4 aR = MFMA16(A0, Br0, Cr); aR = MFMA16(A1, Br1, aR);
                f32x4 aZ = MFMA16(A0, Bz0, Cz); aZ = MFMA16(A1, Bz1, aZ);
                f32x4 aN = MFMA16(A0, Bn0, Cn); aN = MFMA16(A1, Bn1, aN);
                // C row quad*4 -> chain quad>>1 = cch; use acc[0]
                const float xv = (float)s_x[t][cch];
                const float ea = fast_exp2(fmaf(twr, xv, aR[0]));   // e^{-ar}
                const float eb = fast_exp2(fmaf(twz, xv, aZ[0]));   // e^{-az}
                const float d1 = 1.0f + ea, d2 = 1.0f + eb;
                const float inv = fast_rcp(d1 * d2);
                const float rg = d2 * inv, zg = d1 * inv;
                const float nx = fmaf(twn, xv, tbn);
                const float ec = fast_exp2(fmaf(rg, aN[0], nx));    // e^{2an}
                const float nn = fmaf(-2.0f, fast_rcp(ec + 1.0f), 1.0f);
                h1s = nn + zg * (h1s - nn);
                s_h1[t & 1][cch][un] = (_Float16)h1s;   // 2 dup lanes, same value
            }
            __syncthreads();
        }
    } else {
        // ================= GRU2, units (wid-4)*16+nl, one step behind ==========
        const int vn = (wid - 4) * 16 + nl;  // this lane's output unit (n-col)
        const half8 BiR0 = load_w8s(W_ih2 + (size_t)(vn)      * 64 + quad * 8,      SNEG);
        const half8 BiR1 = load_w8s(W_ih2 + (size_t)(vn)      * 64 + 32 + quad * 8, SNEG);
        const half8 BiZ0 = load_w8s(W_ih2 + (size_t)(32 + vn) * 64 + quad * 8,      SNEG);
        const half8 BiZ1 = load_w8s(W_ih2 + (size_t)(32 + vn) * 64 + 32 + quad * 8, SNEG);
        const half8 BiN0 = load_w8s(W_ih2 + (size_t)(64 + vn) * 64 + quad * 8,      SP2);
        const half8 BiN1 = load_w8s(W_ih2 + (size_t)(64 + vn) * 64 + 32 + quad * 8, SP2);
        const half8 BhR  = load_w8s(W_hh2 + (size_t)(vn)      * 32 + quad * 8,      SNEG);
        const half8 BhZ  = load_w8s(W_hh2 + (size_t)(32 + vn) * 32 + quad * 8,      SNEG);
        const half8 BhN  = load_w8s(W_hh2 + (size_t)(64 + vn) * 32 + quad * 8,      SP2);
        const float gr  = SNEG * (b_ih2[vn] + b_hh2[vn]);
        const float gz  = SNEG * (b_ih2[32 + vn] + b_hh2[32 + vn]);
        const float gnx = SP2 * b_ih2[64 + vn];
        const float gnh = SP2 * b_hh2[64 + vn];
        const f32x4 Gr  = {gr, gr, gr, gr};
        const f32x4 Gz  = {gz, gz, gz, gz};
        const f32x4 Gnx = {gnx, gnx, gnx, gnx};
        const f32x4 Gnh = {gnh, gnh, gnh, gnh};

        float h2s = 0.0f;   // h2[chain=cch][unit=vn]

        for (int t = 0; t <= TSTEPS; ++t) {
            if (t >= 1) {
                const int pA = (t + 1) & 1;            // parity of h1(t-1)
                const half8 A0 = *(const half8*)&s_h1[pA][ac][quad * 8];
                const half8 A1 = *(const half8*)&s_h1[pA][ac][32 + quad * 8];
                const half8 Ah = *(const half8*)&s_h2[t & 1][ac][quad * 8];   // h2(t-2)
                f32x4 aR = MFMA16(A0, BiR0, Gr);  aR = MFMA16(A1, BiR1, aR);
                aR = MFMA16(Ah, BhR, aR);
                f32x4 aZ = MFMA16(A0, BiZ0, Gz);  aZ = MFMA16(A1, BiZ1, aZ);
                aZ = MFMA16(Ah, BhZ, aZ);
                f32x4 aNx = MFMA16(A0, BiN0, Gnx); aNx = MFMA16(A1, BiN1, aNx);
                f32x4 aNh = MFMA16(Ah, BhN, Gnh);
                const float ea = fast_exp2(aR[0]);
                const float eb = fast_exp2(aZ[0]);
                const float d1 = 1.0f + ea, d2 = 1.0f + eb;
                const float inv = fast_rcp(d1 * d2);
                const float rg = d2 * inv, zg = d1 * inv;
                const float ec = fast_exp2(fmaf(rg, aNh[0], aNx[0]));
                const float n2 = fmaf(-2.0f, fast_rcp(ec + 1.0f), 1.0f);
                h2s = n2 + zg * (h2s - n2);
                s_h2[(t + 1) & 1][cch][vn] = (_Float16)h2s;   // h2(t-1), dup-safe
            }
            __syncthreads();
        }

        // lane holds h2 for (chain=cch, unit=vn); one of the 2 dup lanes stores
        if ((quad & 1) == 0) {
            out[(size_t)(chain0 + cch) * 32 + vn] = h2s;
        }
    }
}

extern "C" void kernel_launch(void* const* d_in, const int* in_sizes, int n_in,
                              void* d_out, int out_size, void* d_ws, size_t ws_size,
                              hipStream_t stream) {
    const float* x     = (const float*)d_in[0];
    const float* W_ih1 = (const float*)d_in[1];
    const float* W_hh1 = (const float*)d_in[2];
    const float* b_ih1 = (const float*)d_in[3];
    const float* b_hh1 = (const float*)d_in[4];
    const float* W_ih2 = (const float*)d_in[5];
    const float* W_hh2 = (const float*)d_in[6];
    const float* b_ih2 = (const float*)d_in[7];
    const float* b_hh2 = (const float*)d_in[8];
    float* out = (float*)d_out;

    gru2_encoder<<<dim3(1024 / CH), dim3(384), 0, stream>>>(
        x, W_ih1, W_hh1, b_ih1, b_hh1, W_ih2, W_hh2, b_ih2, b_hh2, out);
}

// Round 7
// 332.487 us; speedup vs baseline: 1.2295x; 1.2295x over previous
//
#include <hip/hip_runtime.h>

#define TSTEPS 1024
#define CH 4               // chains per block; replicated 4x across MFMA m-rows

typedef _Float16 half8  __attribute__((ext_vector_type(8)));
typedef float    f32x4  __attribute__((ext_vector_type(4)));

#define MFMA16(A_, B_, C_) __builtin_amdgcn_mfma_f32_16x16x32_f16((A_), (B_), (C_), 0, 0, 0)

__device__ __forceinline__ float fast_rcp(float x) { return __builtin_amdgcn_rcpf(x); }
__device__ __forceinline__ float fast_exp2(float x) {
#if __has_builtin(__builtin_amdgcn_exp2f)
    return __builtin_amdgcn_exp2f(x);
#else
    return exp2f(x);
#endif
}

// load 8 consecutive fp32, scale, convert to packed f16 MFMA fragment
__device__ __forceinline__ half8 load_w8s(const float* p, float s) {
    const float4 a = ((const float4*)p)[0];
    const float4 b = ((const float4*)p)[1];
    half8 r;
    r[0] = (_Float16)(s * a.x); r[1] = (_Float16)(s * a.y);
    r[2] = (_Float16)(s * a.z); r[3] = (_Float16)(s * a.w);
    r[4] = (_Float16)(s * b.x); r[5] = (_Float16)(s * b.y);
    r[6] = (_Float16)(s * b.z); r[7] = (_Float16)(s * b.w);
    return r;
}

// R20 = R17 (best: 272us rocprof; operand-swapped MFMA, row-replicated A,
// in-register preacts, 1 gate-triple/lane, 256 blocks x CH=4, 6 waves,
// 1 barrier/tick) + two LONG-POLE-ONLY fixes, decoupling R18's confounded
// pair (R18 bundled a rebalance that created G1-G1 same-SIMD collisions):
//  1) GRU2-ONLY PARALLEL PARTIALS: G2's 3-deep dependent MFMA chains ->
//     independent C=0 partials + 5 scalar adds (lane uses only acc[0]).
//     Cuts ~2 MFMA latencies from the longest per-tick chain. G1 keeps
//     R17's chained accumulation (its partials cost VALU for nothing).
//  2) s_setprio(1) ON GRU2 WAVES (set once): SIMDs 0,1 host a G1+G2 pair
//     (wid%4 placement); the long-pole G2 wave wins issue arbitration,
//     the short-pole G1 wave absorbs the delay off the critical path
//     (T5 regime: role-diverse waves per SIMD -- holds here).
// R19 post-mortem (CH=2, 2 blocks/CU, 385us): utilization counters rose
// only because per-chain MFMA work doubled; co-resident blocks contend
// (3 waves/SIMD phase-aligned bursts). CH=4 @ 1 block/CU is the sweet
// spot: MFMA-tile amortization (4 chains/tile) beats TLP.
// MFMA layouts (m89/m120/R16-verified): A[m=lane&15][k=quad*8+j],
// B[k=quad*8+j][n=lane&15], C/D: col(n)=lane&15, row(m)=quad*4+reg.
// A = h1(t-1) with chain nl>>2 replicated over 4 m-rows -> lane's C rows
// are 4 identical copies of (chain=quad, unit=nl)'s preact; use acc[0].
// LDS strides 80/48 (uniform 2-way). R8 parity: at tick t, h1(t-1) in
// s_h1[(t+1)&1]; GRU2 reads h2(t-2) from s_h2[t&1], writes h2(t-1) to
// s_h2[(t+1)&1]. exp2 pre-scaled gates (R10).
__global__ __launch_bounds__(384, 1)
void gru2_encoder(const float* __restrict__ x,
                  const float* __restrict__ W_ih1,
                  const float* __restrict__ W_hh1,
                  const float* __restrict__ b_ih1,
                  const float* __restrict__ b_hh1,
                  const float* __restrict__ W_ih2,
                  const float* __restrict__ W_hh2,
                  const float* __restrict__ b_ih2,
                  const float* __restrict__ b_hh2,
                  float* __restrict__ out)
{
    const int blk  = blockIdx.x;    // 256 blocks, CH=4 chains each
    const int tid  = threadIdx.x;   // 384
    const int lane = tid & 63;
    const int wid  = tid >> 6;      // 0..5
    const int nl   = lane & 15;     // MFMA non-k lane index (unit col)
    const int quad = lane >> 4;     // 0..3 (= this lane's gate CHAIN)
    const int ac   = nl >> 2;       // chain this lane's A-row replicates
    const int chain0 = blk * CH;

    const float SNEG = -1.44269504f;       // -log2(e)
    const float SP2  =  2.88539008f;       // 2*log2(e)

    // strides padded for uniform 2-way bank access
    __shared__ __align__(16) _Float16 s_h1[2][4][80];   // [par][chain][unit64 pad80]
    __shared__ __align__(16) _Float16 s_h2[2][4][48];   // [par][chain][unit32 pad48]
    __shared__ __align__(16) _Float16 s_x[TSTEPS][4];   // x f16, [t][chain]

    // ---- one-time staging
    for (int idx = tid; idx < 4 * TSTEPS; idx += 384) {
        const int m = idx >> 10, t = idx & (TSTEPS - 1);
        s_x[t][m] = (_Float16)x[(size_t)(chain0 + m) * TSTEPS + t];
    }
    {
        _Float16* p1 = &s_h1[0][0][0];
        for (int idx = tid; idx < 2 * 4 * 80; idx += 384) p1[idx] = (_Float16)0.0f;
        _Float16* p2 = &s_h2[0][0][0];
        for (int idx = tid; idx < 2 * 4 * 48; idx += 384) p2[idx] = (_Float16)0.0f;
    }
    __syncthreads();

    if (wid < 4) {
        // ================= GRU1, unit-tile wid: units wid*16+nl =================
        const int un = wid * 16 + nl;        // this lane's output unit (n-col)
        // weights as B operand: B[k=quad*8+jj][n=nl] = W_hh1[un][k] (pre-scaled)
        const half8 Br0 = load_w8s(W_hh1 + (size_t)(un)        * 64 + quad * 8,      SNEG);
        const half8 Br1 = load_w8s(W_hh1 + (size_t)(un)        * 64 + 32 + quad * 8, SNEG);
        const half8 Bz0 = load_w8s(W_hh1 + (size_t)(64 + un)   * 64 + quad * 8,      SNEG);
        const half8 Bz1 = load_w8s(W_hh1 + (size_t)(64 + un)   * 64 + 32 + quad * 8, SNEG);
        const half8 Bn0 = load_w8s(W_hh1 + (size_t)(128 + un)  * 64 + quad * 8,      SP2);
        const half8 Bn1 = load_w8s(W_hh1 + (size_t)(128 + un)  * 64 + 32 + quad * 8, SP2);
        // bias depends on unit (col) only -> splat across the 4 C rows
        const float cr = SNEG * (b_ih1[un] + b_hh1[un]);
        const float cz = SNEG * (b_ih1[64 + un] + b_hh1[64 + un]);
        const float cn = SP2 * b_hh1[128 + un];
        const f32x4 Cr = {cr, cr, cr, cr};
        const f32x4 Cz = {cz, cz, cz, cz};
        const f32x4 Cn = {cn, cn, cn, cn};
        // x-path scalars for this lane's unit
        const float twr = SNEG * W_ih1[un];
        const float twz = SNEG * W_ih1[64 + un];
        const float twn = SP2  * W_ih1[128 + un];
        const float tbn = SP2  * b_ih1[128 + un];

        float h1s = 0.0f;   // h1[chain=quad][unit=un]

        for (int t = 0; t <= TSTEPS; ++t) {
            if (t < TSTEPS) {
                const int pr = (t + 1) & 1;
                // A = h1(t-1), chain replicated over 4 rows: A[m=nl] = h1[nl>>2][k]
                const half8 A0 = *(const half8*)&s_h1[pr][ac][quad * 8];
                const half8 A1 = *(const half8*)&s_h1[pr][ac][32 + quad * 8];
                f32x4 aR = MFMA16(A0, Br0, Cr); aR = MFMA16(A1, Br1, aR);
                f32x4 aZ = MFMA16(A0, Bz0, Cz); aZ = MFMA16(A1, Bz1, aZ);
                f32x4 aN = MFMA16(A0, Bn0, Cn); aN = MFMA16(A1, Bn1, aN);
                // C rows 4*quad..4*quad+3 all equal chain quad -> use reg 0
                const float xv = (float)s_x[t][quad];
                const float ea = fast_exp2(fmaf(twr, xv, aR[0]));   // e^{-ar}
                const float eb = fast_exp2(fmaf(twz, xv, aZ[0]));   // e^{-az}
                const float d1 = 1.0f + ea, d2 = 1.0f + eb;
                const float inv = fast_rcp(d1 * d2);
                const float rg = d2 * inv, zg = d1 * inv;
                const float nx = fmaf(twn, xv, tbn);
                const float ec = fast_exp2(fmaf(rg, aN[0], nx));    // e^{2an}
                const float nn = fmaf(-2.0f, fast_rcp(ec + 1.0f), 1.0f);
                h1s = nn + zg * (h1s - nn);
                s_h1[t & 1][quad][un] = (_Float16)h1s;
            }
            __syncthreads();
        }
    } else {
        // ================= GRU2, units (wid-4)*16+nl, one step behind ==========
        __builtin_amdgcn_s_setprio(1);       // long-pole wave: win issue arbitration
        const int vn = (wid - 4) * 16 + nl;  // this lane's output unit (n-col)
        const half8 BiR0 = load_w8s(W_ih2 + (size_t)(vn)      * 64 + quad * 8,      SNEG);
        const half8 BiR1 = load_w8s(W_ih2 + (size_t)(vn)      * 64 + 32 + quad * 8, SNEG);
        const half8 BiZ0 = load_w8s(W_ih2 + (size_t)(32 + vn) * 64 + quad * 8,      SNEG);
        const half8 BiZ1 = load_w8s(W_ih2 + (size_t)(32 + vn) * 64 + 32 + quad * 8, SNEG);
        const half8 BiN0 = load_w8s(W_ih2 + (size_t)(64 + vn) * 64 + quad * 8,      SP2);
        const half8 BiN1 = load_w8s(W_ih2 + (size_t)(64 + vn) * 64 + 32 + quad * 8, SP2);
        const half8 BhR  = load_w8s(W_hh2 + (size_t)(vn)      * 32 + quad * 8,      SNEG);
        const half8 BhZ  = load_w8s(W_hh2 + (size_t)(32 + vn) * 32 + quad * 8,      SNEG);
        const half8 BhN  = load_w8s(W_hh2 + (size_t)(64 + vn) * 32 + quad * 8,      SP2);
        const float gr  = SNEG * (b_ih2[vn] + b_hh2[vn]);
        const float gz  = SNEG * (b_ih2[32 + vn] + b_hh2[32 + vn]);
        const float gnx = SP2 * b_ih2[64 + vn];
        const float gnh = SP2 * b_hh2[64 + vn];
        const f32x4 Gr  = {gr, gr, gr, gr};
        const f32x4 Gz  = {gz, gz, gz, gz};
        const f32x4 Gnx = {gnx, gnx, gnx, gnx};
        const f32x4 Gnh = {gnh, gnh, gnh, gnh};
        const f32x4 Zf  = {0.0f, 0.0f, 0.0f, 0.0f};

        float h2s = 0.0f;   // h2[chain=quad][unit=vn]

        for (int t = 0; t <= TSTEPS; ++t) {
            if (t >= 1) {
                const int pA = (t + 1) & 1;            // parity of h1(t-1)
                const half8 A0 = *(const half8*)&s_h1[pA][ac][quad * 8];
                const half8 A1 = *(const half8*)&s_h1[pA][ac][32 + quad * 8];
                const half8 Ah = *(const half8*)&s_h2[t & 1][ac][quad * 8];   // h2(t-2)
                // GRU2-only parallel partials: no MFMA->MFMA chains (fix 1)
                const f32x4 aRa = MFMA16(A0, BiR0, Gr);
                const f32x4 aRb = MFMA16(A1, BiR1, Zf);
                const f32x4 aRc = MFMA16(Ah, BhR, Zf);
                const f32x4 aZa = MFMA16(A0, BiZ0, Gz);
                const f32x4 aZb = MFMA16(A1, BiZ1, Zf);
                const f32x4 aZc = MFMA16(Ah, BhZ, Zf);
                const f32x4 aNxa = MFMA16(A0, BiN0, Gnx);
                const f32x4 aNxb = MFMA16(A1, BiN1, Zf);
                const f32x4 aNh  = MFMA16(Ah, BhN, Gnh);
                const float pR  = aRa[0] + aRb[0] + aRc[0];
                const float pZ  = aZa[0] + aZb[0] + aZc[0];
                const float pNx = aNxa[0] + aNxb[0];
                const float pNh = aNh[0];
                const float ea = fast_exp2(pR);
                const float eb = fast_exp2(pZ);
                const float d1 = 1.0f + ea, d2 = 1.0f + eb;
                const float inv = fast_rcp(d1 * d2);
                const float rg = d2 * inv, zg = d1 * inv;
                const float ec = fast_exp2(fmaf(rg, pNh, pNx));
                const float n2 = fmaf(-2.0f, fast_rcp(ec + 1.0f), 1.0f);
                h2s = n2 + zg * (h2s - n2);
                s_h2[(t + 1) & 1][quad][vn] = (_Float16)h2s;   // h2(t-1)
            }
            __syncthreads();
        }

        // lane holds h2 for (chain=quad, unit=vn): coalesced b32 stores
        out[(size_t)(chain0 + quad) * 32 + vn] = h2s;
    }
}

extern "C" void kernel_launch(void* const* d_in, const int* in_sizes, int n_in,
                              void* d_out, int out_size, void* d_ws, size_t ws_size,
                              hipStream_t stream) {
    const float* x     = (const float*)d_in[0];
    const float* W_ih1 = (const float*)d_in[1];
    const float* W_hh1 = (const float*)d_in[2];
    const float* b_ih1 = (const float*)d_in[3];
    const float* b_hh1 = (const float*)d_in[4];
    const float* W_ih2 = (const float*)d_in[5];
    const float* W_hh2 = (const float*)d_in[6];
    const float* b_ih2 = (const float*)d_in[7];
    const float* b_hh2 = (const float*)d_in[8];
    float* out = (float*)d_out;

    gru2_encoder<<<dim3(1024 / CH), dim3(384), 0, stream>>>(
        x, W_ih1, W_hh1, b_ih1, b_hh1, W_ih2, W_hh2, b_ih2, b_hh2, out);
}